// Round 1
// baseline (866.833 us; speedup 1.0000x reference)
//
#include <hip/hip_runtime.h>

// Problem constants: B=4, C=64, Z=H=W=64, modes 16, rank 16.
#define TWOPI 6.28318530717958647692f

// cos/sin(2*pi*k/64) as constexpr (compile-time literals after full unroll)
constexpr float COSQ[17] = {
  1.0f, 0.995184727f, 0.980785280f, 0.956940336f, 0.923879533f,
  0.881921264f, 0.831469612f, 0.773010453f, 0.707106781f,
  0.634393284f, 0.555570233f, 0.471396737f, 0.382683432f,
  0.290284677f, 0.195090322f, 0.098017140f, 0.0f
};
__host__ __device__ constexpr float cos64f(int k) {
  k &= 63;
  return (k <= 16) ? COSQ[k] : (k < 32) ? -COSQ[32 - k]
       : (k <= 48) ? -COSQ[k - 32] : COSQ[64 - k];
}
__host__ __device__ constexpr float sin64f(int k) { return cos64f(k + 48); }

// ---------------- core sums: S1 = sum(core_r)+i sum(core_i), S2 likewise ---
__global__ __launch_bounds__(256) void k_core_partial(
    const float* __restrict__ a0, const float* __restrict__ a1,
    const float* __restrict__ a2, const float* __restrict__ a3,
    float* __restrict__ partial) {
  const float* p = blockIdx.y == 0 ? a0 : blockIdx.y == 1 ? a1
                 : blockIdx.y == 2 ? a2 : a3;
  const float4* p4 = (const float4*)p;
  float s = 0.f;
  int base = blockIdx.x * 4096 + threadIdx.x;   // 64 blocks * 4096 float4
  #pragma unroll
  for (int i = 0; i < 16; ++i) {
    float4 v = p4[base + i * 256];
    s += (v.x + v.y) + (v.z + v.w);
  }
  __shared__ float red[256];
  red[threadIdx.x] = s;
  __syncthreads();
  for (int off = 128; off; off >>= 1) {
    if (threadIdx.x < off) red[threadIdx.x] += red[threadIdx.x + off];
    __syncthreads();
  }
  if (threadIdx.x == 0) partial[blockIdx.y * 64 + blockIdx.x] = red[0];
}

__global__ void k_core_final(const float* __restrict__ partial,
                             float* __restrict__ S) {
  int t = threadIdx.x;
  if (t < 4) {
    float s = 0.f;
    for (int j = 0; j < 64; ++j) s += partial[t * 64 + j];
    S[t] = s;
  }
}

// ---------------- forward W+H DFT: x(b,c,z,:,:) -> A2[b,c,z,hf,wf] ---------
// wave (64 lanes) = one (h,w) plane; 4 planes per 256-thread block.
__global__ __launch_bounds__(256) void k_fwd_wh(const float* __restrict__ x,
                                                float2* __restrict__ A2) {
  __shared__ float2 T[4][64][17];   // pad 17: conflict-free
  int wave = threadIdx.x >> 6, lane = threadIdx.x & 63;
  int plane = blockIdx.x * 4 + wave;            // (b*64+c)*64+z
  const float* rowp = x + (size_t)plane * 4096 + lane * 64;  // lane = h
  float r[64];
  #pragma unroll
  for (int k = 0; k < 16; ++k) {
    float4 v = ((const float4*)rowp)[k];
    r[4 * k] = v.x; r[4 * k + 1] = v.y; r[4 * k + 2] = v.z; r[4 * k + 3] = v.w;
  }
  // stage 1: real DFT over w, 16 freqs, literal twiddles + x[w]/x[64-w] pairing
  float tre[16], tim[16];
  #pragma unroll
  for (int wf = 0; wf < 16; ++wf) {
    tre[wf] = r[0] + ((wf & 1) ? -r[32] : r[32]);
    tim[wf] = 0.f;
  }
  #pragma unroll
  for (int w = 1; w < 32; ++w) {
    float u = r[w] + r[64 - w], v = r[w] - r[64 - w];
    #pragma unroll
    for (int wf = 0; wf < 16; ++wf) {
      tre[wf] = fmaf(u, cos64f(w * wf), tre[wf]);
      tim[wf] = fmaf(v, -sin64f(w * wf), tim[wf]);
    }
  }
  #pragma unroll
  for (int wf = 0; wf < 16; ++wf)
    T[wave][lane][wf] = make_float2(tre[wf], tim[wf]);
  __syncthreads();
  // stage 2: complex DFT over h, 16 freqs. lane=(wf, hfg); hf_j = hfg+4j.
  int wf = lane & 15, hfg = lane >> 4;
  float2 E[4], St[4], acc[4];
  #pragma unroll
  for (int j = 0; j < 4; ++j) {
    float s, c;
    sincosf(-(TWOPI / 64.f) * (float)(hfg + 4 * j), &s, &c);
    St[j] = make_float2(c, s);                 // e^{-2pi i hf/64}
    E[j] = make_float2(1.f, 0.f);
    acc[j] = make_float2(0.f, 0.f);
  }
  for (int h = 0; h < 64; ++h) {
    float2 a = T[wave][h][wf];
    #pragma unroll
    for (int j = 0; j < 4; ++j) {
      acc[j].x = fmaf(a.x, E[j].x, fmaf(-a.y, E[j].y, acc[j].x));
      acc[j].y = fmaf(a.x, E[j].y, fmaf(a.y, E[j].x, acc[j].y));
      float ex = E[j].x * St[j].x - E[j].y * St[j].y;
      E[j].y = fmaf(E[j].x, St[j].y, E[j].y * St[j].x);
      E[j].x = ex;
    }
  }
  float2* dst = A2 + (size_t)plane * 256;
  #pragma unroll
  for (int j = 0; j < 4; ++j) dst[(hfg + 4 * j) * 16 + wf] = acc[j];
}

// ---------------- forward Z DFT: A2[b,c,z,t] -> A3[b,c,zf(32),t] -----------
// zf 0..15 -> freq zf (lo); zf 16..31 -> freq zf+32 (48..63, hi).
// e^{-2pi i z(k+48)/64} = e^{-2pi i zk/64} * i^z
__global__ __launch_bounds__(256) void k_fwd_z(const float2* __restrict__ A2,
                                               float2* __restrict__ A3) {
  int bc = blockIdx.x, t = threadIdx.x;
  const float2* src = A2 + (size_t)bc * 16384 + t;
  float2 acc[32];
  #pragma unroll
  for (int k = 0; k < 32; ++k) acc[k] = make_float2(0.f, 0.f);
  for (int z = 0; z < 64; ++z) {
    float2 v = src[(size_t)z * 256];
    int zm = z & 3;   // vr = v * i^z
    float2 vr = (zm == 0) ? v
              : (zm == 1) ? make_float2(-v.y, v.x)
              : (zm == 2) ? make_float2(-v.x, -v.y)
                          : make_float2(v.y, -v.x);
    float s, c;
    sincosf(-(TWOPI / 64.f) * (float)z, &s, &c);   // step e^{-2pi i z/64}
    float2 E = make_float2(1.f, 0.f);
    #pragma unroll
    for (int k = 0; k < 16; ++k) {
      acc[k].x = fmaf(v.x, E.x, fmaf(-v.y, E.y, acc[k].x));
      acc[k].y = fmaf(v.x, E.y, fmaf(v.y, E.x, acc[k].y));
      acc[k + 16].x = fmaf(vr.x, E.x, fmaf(-vr.y, E.y, acc[k + 16].x));
      acc[k + 16].y = fmaf(vr.x, E.y, fmaf(vr.y, E.x, acc[k + 16].y));
      float ex = E.x * c - E.y * s;
      E.y = fmaf(E.x, s, E.y * c);
      E.x = ex;
    }
  }
  float2* dst = A3 + (size_t)bc * 8192 + t;
  #pragma unroll
  for (int k = 0; k < 32; ++k) dst[(size_t)k * 256] = acc[k];
}

// ---------------- rank-16 channel mix ---------------------------------------
// G[b,o,zf,t] = sum_r U_out[o,r]*f[r]*sum_c U_in[c,r]*A3[b,c,zf,t]
// f[r] = S*invN * Uz[zf,r]*U_w[hf,r]*Uh[wf,r]  (lo) / z2,h2,S2 (hi)
__global__ __launch_bounds__(256) void k_mix(
    const float2* __restrict__ A3, float2* __restrict__ G,
    const float* __restrict__ U_in, const float* __restrict__ U_out,
    const float* __restrict__ U_z, const float* __restrict__ U_h,
    const float* __restrict__ U_w, const float* __restrict__ U_z2,
    const float* __restrict__ U_h2, const float* __restrict__ S4) {
  int b = blockIdx.x >> 5, zf = blockIdx.x & 31;
  int t = threadIdx.x, hf = t >> 4, wf = t & 15;
  const float2* src = A3 + ((size_t)b * 2048 + zf) * 256 + t;
  float2 acc[16];
  #pragma unroll
  for (int r = 0; r < 16; ++r) acc[r] = make_float2(0.f, 0.f);
  for (int c = 0; c < 64; ++c) {
    float2 v = src[(size_t)c * 8192];
    #pragma unroll
    for (int r = 0; r < 16; ++r) {
      float u = U_in[c * 16 + r];
      acc[r].x = fmaf(v.x, u, acc[r].x);
      acc[r].y = fmaf(v.y, u, acc[r].y);
    }
  }
  float Sre, Sim; const float *Uzp, *Uhq; int zq;
  if (zf < 16) { Sre = S4[0]; Sim = S4[1]; Uzp = U_z;  Uhq = U_h;  zq = zf; }
  else         { Sre = S4[2]; Sim = S4[3]; Uzp = U_z2; Uhq = U_h2; zq = zf - 16; }
  const float invN = 1.0f / 262144.0f;     // 1/(64*64*64) irfftn norm
  Sre *= invN; Sim *= invN;
  #pragma unroll
  for (int r = 0; r < 16; ++r) {
    float gf = Uzp[zq * 16 + r] * U_w[hf * 16 + r] * Uhq[wf * 16 + r];
    float fre = Sre * gf, fim = Sim * gf;
    float xr = acc[r].x, xi = acc[r].y;
    acc[r].x = xr * fre - xi * fim;
    acc[r].y = xr * fim + xi * fre;
  }
  float2* dst = G + ((size_t)b * 2048 + zf) * 256 + t;
  for (int o = 0; o < 64; ++o) {
    float re = 0.f, im = 0.f;
    #pragma unroll
    for (int r = 0; r < 16; ++r) {
      float u = U_out[o * 16 + r];
      re = fmaf(acc[r].x, u, re);
      im = fmaf(acc[r].y, u, im);
    }
    dst[(size_t)o * 8192] = make_float2(re, im);
  }
}

// ---------------- inverse Z: G[b,o,zf(32),t] -> Bz[b,o,z(64),t] -------------
// e^{+2pi i z(k+48)/64} = e^{+2pi i zk/64} * (-i)^z
__global__ __launch_bounds__(256) void k_inv_z(const float2* __restrict__ G,
                                               float2* __restrict__ Bz) {
  int bo = blockIdx.x, t = threadIdx.x;
  const float2* src = G + (size_t)bo * 8192 + t;
  float2 g[32];
  #pragma unroll
  for (int k = 0; k < 32; ++k) g[k] = src[(size_t)k * 256];
  float2* dst = Bz + (size_t)bo * 16384 + t;
  for (int z = 0; z < 64; ++z) {
    float s, c;
    sincosf((TWOPI / 64.f) * (float)z, &s, &c);   // step e^{+2pi i z/64}
    float2 E = make_float2(1.f, 0.f);
    float2 ov = make_float2(0.f, 0.f);
    int zm = z & 3;
    #pragma unroll
    for (int k = 0; k < 16; ++k) {
      float2 bb = g[k + 16];   // rotate by (-i)^z
      float2 br = (zm == 0) ? bb
                : (zm == 1) ? make_float2(bb.y, -bb.x)
                : (zm == 2) ? make_float2(-bb.x, -bb.y)
                            : make_float2(-bb.y, bb.x);
      float gx = g[k].x + br.x, gy = g[k].y + br.y;
      ov.x = fmaf(gx, E.x, fmaf(-gy, E.y, ov.x));
      ov.y = fmaf(gx, E.y, fmaf(gy, E.x, ov.y));
      float ex = E.x * c - E.y * s;
      E.y = fmaf(E.x, s, E.y * c);
      E.x = ex;
    }
    dst[(size_t)z * 256] = ov;
  }
}

// ---------------- inverse H + real inverse W: Bz plane -> out plane ---------
__global__ __launch_bounds__(256) void k_inv_hw(const float2* __restrict__ Bz,
                                                float* __restrict__ out) {
  __shared__ float2 TH[4][64][17];
  int wave = threadIdx.x >> 6, lane = threadIdx.x & 63;
  int plane = blockIdx.x * 4 + wave;            // (b*64+o)*64+z
  const float2* csp = Bz + (size_t)plane * 256;
  // iH: lane = (wf, hq); Th[h][wf] = sum_hf cs[hf][wf] e^{+2pi i h hf/64}
  int wf = lane & 15, hq = lane >> 4;
  float2 col[16];
  #pragma unroll
  for (int hf = 0; hf < 16; ++hf) col[hf] = csp[hf * 16 + wf];
  #pragma unroll 1
  for (int i = 0; i < 16; ++i) {
    int h = hq * 16 + i;
    float s, c;
    sincosf((TWOPI / 64.f) * (float)h, &s, &c);
    float2 E = make_float2(1.f, 0.f);
    float2 acc = make_float2(0.f, 0.f);
    #pragma unroll
    for (int hf = 0; hf < 16; ++hf) {
      acc.x = fmaf(col[hf].x, E.x, fmaf(-col[hf].y, E.y, acc.x));
      acc.y = fmaf(col[hf].x, E.y, fmaf(col[hf].y, E.x, acc.y));
      float ex = E.x * c - E.y * s;
      E.y = fmaf(E.x, s, E.y * c);
      E.x = ex;
    }
    TH[wave][h][wf] = acc;
  }
  __syncthreads();
  // iW: lane = h. out[w] = Re(T0) + 2 sum_{wf>=1} Re(T_wf e^{+2pi i w wf/64})
  float ar[16], ai[16];
  #pragma unroll
  for (int q = 0; q < 16; ++q) {
    float2 a = TH[wave][lane][q];
    ar[q] = a.x; ai[q] = a.y;
  }
  float* op = out + (size_t)plane * 4096 + lane * 64;
  {
    float P = ar[0];
    #pragma unroll
    for (int q = 1; q < 16; ++q) P += 2.f * ar[q];
    op[0] = P;
  }
  {
    float P = ar[0];
    #pragma unroll
    for (int q = 1; q < 16; ++q) P = fmaf(ar[q], (q & 1) ? -2.f : 2.f, P);
    op[32] = P;
  }
  #pragma unroll
  for (int w = 1; w < 32; ++w) {
    float P = ar[0], Q = 0.f;
    #pragma unroll
    for (int q = 1; q < 16; ++q) {
      P = fmaf(ar[q], 2.f * cos64f(w * q), P);
      Q = fmaf(ai[q], 2.f * sin64f(w * q), Q);
    }
    op[w] = P - Q;
    op[64 - w] = P + Q;
  }
}

extern "C" void kernel_launch(void* const* d_in, const int* in_sizes, int n_in,
                              void* d_out, int out_size, void* d_ws,
                              size_t ws_size, hipStream_t stream) {
  const float* x    = (const float*)d_in[0];
  const float* Uin  = (const float*)d_in[1];
  const float* Uout = (const float*)d_in[2];
  const float* Uz   = (const float*)d_in[3];
  const float* Uh   = (const float*)d_in[4];
  const float* Uw   = (const float*)d_in[5];
  const float* Uz2  = (const float*)d_in[6];
  const float* Uh2  = (const float*)d_in[7];
  const float* cr   = (const float*)d_in[8];
  const float* ci   = (const float*)d_in[9];
  const float* c2r  = (const float*)d_in[10];
  const float* c2i  = (const float*)d_in[11];
  float* outp = (float*)d_out;

  char* ws = (char*)d_ws;
  float* S       = (float*)ws;            // 4 floats
  float* partial = (float*)(ws + 256);    // 256 floats
  float2* A2 = (float2*)(ws + 4096);                          // 33,554,432 B
  float2* A3 = (float2*)(ws + 4096 + 33554432);               // 16,777,216 B
  float2* G  = (float2*)(ws + 4096 + 33554432 + 16777216);    // 16,777,216 B
  float2* Bz = A2;   // A2 is dead after k_fwd_z; reuse for inverse-Z output

  k_core_partial<<<dim3(64, 4), 256, 0, stream>>>(cr, ci, c2r, c2i, partial);
  k_core_final<<<1, 64, 0, stream>>>(partial, S);
  k_fwd_wh<<<4096, 256, 0, stream>>>(x, A2);
  k_fwd_z<<<256, 256, 0, stream>>>(A2, A3);
  k_mix<<<128, 256, 0, stream>>>(A3, G, Uin, Uout, Uz, Uh, Uw, Uz2, Uh2, S);
  k_inv_z<<<256, 256, 0, stream>>>(G, Bz);
  k_inv_hw<<<4096, 256, 0, stream>>>(Bz, outp);
}

// Round 2
// 294.167 us; speedup vs baseline: 2.9467x; 2.9467x over previous
//
#include <hip/hip_runtime.h>

// Problem constants: B=4, C=64, Z=H=W=64, modes 16, rank 16.
#define TWOPI 6.28318530717958647692f

// cos/sin(2*pi*k/64) as constexpr (compile-time literals after full unroll)
constexpr float COSQ[17] = {
  1.0f, 0.995184727f, 0.980785280f, 0.956940336f, 0.923879533f,
  0.881921264f, 0.831469612f, 0.773010453f, 0.707106781f,
  0.634393284f, 0.555570233f, 0.471396737f, 0.382683432f,
  0.290284677f, 0.195090322f, 0.098017140f, 0.0f
};
__host__ __device__ constexpr float cos64f(int k) {
  k &= 63;
  return (k <= 16) ? COSQ[k] : (k < 32) ? -COSQ[32 - k]
       : (k <= 48) ? -COSQ[k - 32] : COSQ[64 - k];
}
__host__ __device__ constexpr float sin64f(int k) { return cos64f(k + 48); }

// t-layout of the 256 frequency pairs (chosen so fwd_wh stores coalesced):
//   t = j*64 + wq*16 + hf,  wfreq = wq + 4*j,  hfreq = hf
// decode: hf = t&15, wf = ((t>>4)&3) + 4*(t>>6)

// ---------------- core sums ------------------------------------------------
__global__ __launch_bounds__(256) void k_core_partial(
    const float* __restrict__ a0, const float* __restrict__ a1,
    const float* __restrict__ a2, const float* __restrict__ a3,
    float* __restrict__ partial) {
  const float* p = blockIdx.y == 0 ? a0 : blockIdx.y == 1 ? a1
                 : blockIdx.y == 2 ? a2 : a3;
  const float4* p4 = (const float4*)p;
  float s = 0.f;
  int base = blockIdx.x * 4096 + threadIdx.x;
  #pragma unroll
  for (int i = 0; i < 16; ++i) {
    float4 v = p4[base + i * 256];
    s += (v.x + v.y) + (v.z + v.w);
  }
  __shared__ float red[256];
  red[threadIdx.x] = s;
  __syncthreads();
  for (int off = 128; off; off >>= 1) {
    if (threadIdx.x < off) red[threadIdx.x] += red[threadIdx.x + off];
    __syncthreads();
  }
  if (threadIdx.x == 0) partial[blockIdx.y * 64 + blockIdx.x] = red[0];
}

__global__ void k_core_final(const float* __restrict__ partial,
                             float* __restrict__ S) {
  int t = threadIdx.x;
  if (t < 4) {
    float s = 0.f;
    for (int j = 0; j < 64; ++j) s += partial[t * 64 + j];
    S[t] = s;
  }
}

// ---------------- forward H+W DFT: x(b,c,z,:,:) -> A2[plane][t] ------------
// wave = one plane. Stage 1: real DFT over h, lane = w (coalesced loads,
// literal twiddles). Stage 2: complex DFT over w from LDS.
__global__ __launch_bounds__(256) void k_fwd_wh(const float* __restrict__ x,
                                                float2* __restrict__ A2) {
  __shared__ float2 T[4][64][17];   // [w][hf], pad 17
  int wave = threadIdx.x >> 6, lane = threadIdx.x & 63;
  int plane = blockIdx.x * 4 + wave;            // (b*64+c)*64+z
  const float* xp = x + (size_t)plane * 4096 + lane;   // lane = w
  // stage 1: col[hf] = sum_h x[h][w] e^{-2pi i h hf/64}, pairing h / 64-h
  float cre[16], cim[16];
  {
    float x0 = xp[0], x32 = xp[32 * 64];
    #pragma unroll
    for (int hf = 0; hf < 16; ++hf) {
      cre[hf] = x0 + ((hf & 1) ? -x32 : x32);
      cim[hf] = 0.f;
    }
  }
  #pragma unroll
  for (int h = 1; h < 32; ++h) {
    float va = xp[h * 64], vb = xp[(64 - h) * 64];
    float u = va + vb, d = va - vb;
    #pragma unroll
    for (int hf = 0; hf < 16; ++hf) {
      cre[hf] = fmaf(u, cos64f(h * hf), cre[hf]);
      cim[hf] = fmaf(d, -sin64f(h * hf), cim[hf]);
    }
  }
  #pragma unroll
  for (int hf = 0; hf < 16; ++hf)
    T[wave][lane][hf] = make_float2(cre[hf], cim[hf]);
  __syncthreads();
  // stage 2: A2[hf][wf] = sum_w T[w][hf] e^{-2pi i w wf/64}; wf = wq+4j
  int hf = lane & 15, wq = lane >> 4;
  float2 E[4], St[4], acc[4];
  #pragma unroll
  for (int j = 0; j < 4; ++j) {
    float s, c;
    sincosf(-(TWOPI / 64.f) * (float)(wq + 4 * j), &s, &c);
    St[j] = make_float2(c, s);
    E[j] = make_float2(1.f, 0.f);
    acc[j] = make_float2(0.f, 0.f);
  }
  for (int w = 0; w < 64; ++w) {
    float2 a = T[wave][w][hf];
    #pragma unroll
    for (int j = 0; j < 4; ++j) {
      acc[j].x = fmaf(a.x, E[j].x, fmaf(-a.y, E[j].y, acc[j].x));
      acc[j].y = fmaf(a.x, E[j].y, fmaf(a.y, E[j].x, acc[j].y));
      float ex = E[j].x * St[j].x - E[j].y * St[j].y;
      E[j].y = fmaf(E[j].x, St[j].y, E[j].y * St[j].x);
      E[j].x = ex;
    }
  }
  // store: t = j*64 + lane  (lane = wq*16+hf) -> coalesced 512B per j
  float2* dst = A2 + (size_t)plane * 256 + lane;
  #pragma unroll
  for (int j = 0; j < 4; ++j) dst[j * 64] = acc[j];
}

// ---------------- forward Z DFT: A2[bc][z][t] -> A3[bc][zf(32)][t] ---------
// blockIdx.y: 0 = lo freqs (0..15), 1 = hi freqs (48..63, via * i^z)
__global__ __launch_bounds__(256) void k_fwd_z(const float2* __restrict__ A2,
                                               float2* __restrict__ A3) {
  int bc = blockIdx.x, t = threadIdx.x, half = blockIdx.y;
  const float2* src = A2 + (size_t)bc * 16384 + t;
  float2 acc[16];
  #pragma unroll
  for (int k = 0; k < 16; ++k) acc[k] = make_float2(0.f, 0.f);
  for (int z = 0; z < 64; ++z) {
    float2 v = src[(size_t)z * 256];
    if (half) {
      int zm = z & 3;   // v *= i^z
      v = (zm == 0) ? v
        : (zm == 1) ? make_float2(-v.y, v.x)
        : (zm == 2) ? make_float2(-v.x, -v.y)
                    : make_float2(v.y, -v.x);
    }
    float s, c;
    sincosf(-(TWOPI / 64.f) * (float)z, &s, &c);
    float2 E = make_float2(1.f, 0.f);
    #pragma unroll
    for (int k = 0; k < 16; ++k) {
      acc[k].x = fmaf(v.x, E.x, fmaf(-v.y, E.y, acc[k].x));
      acc[k].y = fmaf(v.x, E.y, fmaf(v.y, E.x, acc[k].y));
      float ex = E.x * c - E.y * s;
      E.y = fmaf(E.x, s, E.y * c);
      E.x = ex;
    }
  }
  float2* dst = A3 + (size_t)bc * 8192 + (size_t)half * 4096 + t;
  #pragma unroll
  for (int k = 0; k < 16; ++k) dst[(size_t)k * 256] = acc[k];
}

// ---------------- rank-16 channel mix --------------------------------------
// blockIdx.y splits the o-loop in halves.
__global__ __launch_bounds__(256) void k_mix(
    const float2* __restrict__ A3, float2* __restrict__ G,
    const float* __restrict__ U_in, const float* __restrict__ U_out,
    const float* __restrict__ U_z, const float* __restrict__ U_h,
    const float* __restrict__ U_w, const float* __restrict__ U_z2,
    const float* __restrict__ U_h2, const float* __restrict__ S4) {
  int b = blockIdx.x >> 5, zf = blockIdx.x & 31;
  int t = threadIdx.x;
  int hfq = t & 15, wfq = ((t >> 4) & 3) + 4 * (t >> 6);
  const float2* src = A3 + ((size_t)b * 2048 + zf) * 256 + t;
  float2 acc[16];
  #pragma unroll
  for (int r = 0; r < 16; ++r) acc[r] = make_float2(0.f, 0.f);
  for (int c = 0; c < 64; ++c) {
    float2 v = src[(size_t)c * 8192];
    #pragma unroll
    for (int r = 0; r < 16; ++r) {
      float u = U_in[c * 16 + r];
      acc[r].x = fmaf(v.x, u, acc[r].x);
      acc[r].y = fmaf(v.y, u, acc[r].y);
    }
  }
  float Sre, Sim; const float *Uzp, *Uhq; int zq;
  if (zf < 16) { Sre = S4[0]; Sim = S4[1]; Uzp = U_z;  Uhq = U_h;  zq = zf; }
  else         { Sre = S4[2]; Sim = S4[3]; Uzp = U_z2; Uhq = U_h2; zq = zf - 16; }
  const float invN = 1.0f / 262144.0f;     // 1/(64*64*64) irfftn norm
  Sre *= invN; Sim *= invN;
  #pragma unroll
  for (int r = 0; r < 16; ++r) {
    float gf = Uzp[zq * 16 + r] * U_w[hfq * 16 + r] * Uhq[wfq * 16 + r];
    float fre = Sre * gf, fim = Sim * gf;
    float xr = acc[r].x, xi = acc[r].y;
    acc[r].x = xr * fre - xi * fim;
    acc[r].y = xr * fim + xi * fre;
  }
  float2* dst = G + ((size_t)b * 2048 + zf) * 256 + t;
  int o0 = blockIdx.y * 32;
  for (int o = o0; o < o0 + 32; ++o) {
    float re = 0.f, im = 0.f;
    #pragma unroll
    for (int r = 0; r < 16; ++r) {
      float u = U_out[o * 16 + r];
      re = fmaf(acc[r].x, u, re);
      im = fmaf(acc[r].y, u, im);
    }
    dst[(size_t)o * 8192] = make_float2(re, im);
  }
}

// ---------------- inverse Z: G[bo][zf(32)][t] -> Bz[bo][z(64)][t] ----------
// blockIdx.y picks z-range half.
__global__ __launch_bounds__(256) void k_inv_z(const float2* __restrict__ G,
                                               float2* __restrict__ Bz) {
  int bo = blockIdx.x, t = threadIdx.x;
  const float2* src = G + (size_t)bo * 8192 + t;
  float2 g[32];
  #pragma unroll
  for (int k = 0; k < 32; ++k) g[k] = src[(size_t)k * 256];
  float2* dst = Bz + (size_t)bo * 16384 + t;
  int z0 = blockIdx.y * 32;
  for (int z = z0; z < z0 + 32; ++z) {
    float s, c;
    sincosf((TWOPI / 64.f) * (float)z, &s, &c);
    float2 E = make_float2(1.f, 0.f);
    float2 ov = make_float2(0.f, 0.f);
    int zm = z & 3;
    #pragma unroll
    for (int k = 0; k < 16; ++k) {
      float2 bb = g[k + 16];   // rotate by (-i)^z
      float2 br = (zm == 0) ? bb
                : (zm == 1) ? make_float2(bb.y, -bb.x)
                : (zm == 2) ? make_float2(-bb.x, -bb.y)
                            : make_float2(-bb.y, bb.x);
      float gx = g[k].x + br.x, gy = g[k].y + br.y;
      ov.x = fmaf(gx, E.x, fmaf(-gy, E.y, ov.x));
      ov.y = fmaf(gx, E.y, fmaf(gy, E.x, ov.y));
      float ex = E.x * c - E.y * s;
      E.y = fmaf(E.x, s, E.y * c);
      E.x = ex;
    }
    dst[(size_t)z * 256] = ov;
  }
}

// ---------------- inverse H + real inverse W: Bz plane -> out plane --------
// wave = plane; lane = w. q[hf] = g[hf][0] + sum_{wf>=1} g[hf][wf]*2e^{+iθw},
// out[h][w] = Re(sum_hf q[hf] e^{+2pi i h hf/64})  (literal twiddles, h/64-h
// pairing, coalesced dword stores).
__global__ __launch_bounds__(256) void k_inv_hw(const float2* __restrict__ Bz,
                                                float* __restrict__ out) {
  __shared__ float2 GL[4][256];
  int wave = threadIdx.x >> 6, lane = threadIdx.x & 63;
  int plane = blockIdx.x * 4 + wave;            // (b*64+o)*64+z
  // cooperative coalesced load + descramble t -> (hf,wf)
  const float4* p4 = (const float4*)(Bz + (size_t)plane * 256);
  #pragma unroll
  for (int half = 0; half < 2; ++half) {
    float4 v = p4[lane + 64 * half];
    int t0 = 2 * (lane + 64 * half);
    int h0 = t0 & 15, w0 = ((t0 >> 4) & 3) + 4 * (t0 >> 6);
    int t1 = t0 + 1;
    int h1 = t1 & 15, w1 = ((t1 >> 4) & 3) + 4 * (t1 >> 6);
    GL[wave][h0 * 16 + w0] = make_float2(v.x, v.y);
    GL[wave][h1 * 16 + w1] = make_float2(v.z, v.w);
  }
  __syncthreads();
  // E2[wf] = 2 e^{+2pi i w wf/64}, w = lane
  float2 E2[16];   // index 1..15 used
  {
    float s, c;
    sincosf((TWOPI / 64.f) * (float)lane, &s, &c);
    float2 E = make_float2(c, s);
    float2 St = E;
    #pragma unroll
    for (int wf = 1; wf < 16; ++wf) {
      E2[wf] = make_float2(E.x + E.x, E.y + E.y);
      float ex = E.x * St.x - E.y * St.y;
      E.y = fmaf(E.x, St.y, E.y * St.x);
      E.x = ex;
    }
  }
  float qre[16], qim[16];
  #pragma unroll
  for (int hf = 0; hf < 16; ++hf) {
    const float2* gp = &GL[wave][hf * 16];
    float2 g0 = gp[0], g1 = gp[1];
    float ar = g0.x + (g1.x * E2[1].x - g1.y * E2[1].y);
    float ai = g0.y + (g1.x * E2[1].y + g1.y * E2[1].x);
    #pragma unroll
    for (int wf = 2; wf < 16; ++wf) {
      float2 gv = gp[wf];
      ar = fmaf(gv.x, E2[wf].x, fmaf(-gv.y, E2[wf].y, ar));
      ai = fmaf(gv.x, E2[wf].y, fmaf(gv.y, E2[wf].x, ai));
    }
    qre[hf] = ar; qim[hf] = ai;
  }
  // out[h][w] = sum_hf qre*cos(2pi h hf/64) - qim*sin(...)
  float* op = out + (size_t)plane * 4096 + lane;
  {
    float P = qre[0];
    #pragma unroll
    for (int hf = 1; hf < 16; ++hf) P += qre[hf];
    op[0] = P;
  }
  {
    float P = qre[0];
    #pragma unroll
    for (int hf = 1; hf < 16; ++hf) P += (hf & 1) ? -qre[hf] : qre[hf];
    op[32 * 64] = P;
  }
  #pragma unroll
  for (int h = 1; h < 32; ++h) {
    float P = qre[0], Q = 0.f;
    #pragma unroll
    for (int hf = 1; hf < 16; ++hf) {
      P = fmaf(qre[hf], cos64f(h * hf), P);
      Q = fmaf(qim[hf], sin64f(h * hf), Q);
    }
    op[h * 64] = P - Q;
    op[(64 - h) * 64] = P + Q;
  }
}

extern "C" void kernel_launch(void* const* d_in, const int* in_sizes, int n_in,
                              void* d_out, int out_size, void* d_ws,
                              size_t ws_size, hipStream_t stream) {
  const float* x    = (const float*)d_in[0];
  const float* Uin  = (const float*)d_in[1];
  const float* Uout = (const float*)d_in[2];
  const float* Uz   = (const float*)d_in[3];
  const float* Uh   = (const float*)d_in[4];
  const float* Uw   = (const float*)d_in[5];
  const float* Uz2  = (const float*)d_in[6];
  const float* Uh2  = (const float*)d_in[7];
  const float* cr   = (const float*)d_in[8];
  const float* ci   = (const float*)d_in[9];
  const float* c2r  = (const float*)d_in[10];
  const float* c2i  = (const float*)d_in[11];
  float* outp = (float*)d_out;

  char* ws = (char*)d_ws;
  float* S       = (float*)ws;            // 4 floats
  float* partial = (float*)(ws + 256);    // 256 floats
  float2* A2 = (float2*)(ws + 4096);                          // 33,554,432 B
  float2* A3 = (float2*)(ws + 4096 + 33554432);               // 16,777,216 B
  float2* G  = (float2*)(ws + 4096 + 33554432 + 16777216);    // 16,777,216 B
  float2* Bz = A2;   // A2 dead after k_fwd_z; reuse for inverse-Z output

  k_core_partial<<<dim3(64, 4), 256, 0, stream>>>(cr, ci, c2r, c2i, partial);
  k_core_final<<<1, 64, 0, stream>>>(partial, S);
  k_fwd_wh<<<4096, 256, 0, stream>>>(x, A2);
  k_fwd_z<<<dim3(256, 2), 256, 0, stream>>>(A2, A3);
  k_mix<<<dim3(128, 2), 256, 0, stream>>>(A3, G, Uin, Uout, Uz, Uh, Uw, Uz2,
                                          Uh2, S);
  k_inv_z<<<dim3(256, 2), 256, 0, stream>>>(G, Bz);
  k_inv_hw<<<4096, 256, 0, stream>>>(Bz, outp);
}

// Round 3
// 206.301 us; speedup vs baseline: 4.2018x; 1.4259x over previous
//
#include <hip/hip_runtime.h>

// Problem constants: B=4, C=64, Z=H=W=64, modes 16, rank 16.
#define TWOPI 6.28318530717958647692f

// cos/sin(2*pi*k/64) as constexpr (compile-time literals after full unroll)
constexpr float COSQ[17] = {
  1.0f, 0.995184727f, 0.980785280f, 0.956940336f, 0.923879533f,
  0.881921264f, 0.831469612f, 0.773010453f, 0.707106781f,
  0.634393284f, 0.555570233f, 0.471396737f, 0.382683432f,
  0.290284677f, 0.195090322f, 0.098017140f, 0.0f
};
__host__ __device__ constexpr float cos64f(int k) {
  k &= 63;
  return (k <= 16) ? COSQ[k] : (k < 32) ? -COSQ[32 - k]
       : (k <= 48) ? -COSQ[k - 32] : COSQ[64 - k];
}
__host__ __device__ constexpr float sin64f(int k) { return cos64f(k + 48); }

// t-layout of the 256 (hf,wf) pairs:  t = j*64 + wq*16 + hf, wf = wq+4j.
// decode: hf = t&15, wf = ((t>>4)&3) + 4*(t>>6)

// ---------------- core sums ------------------------------------------------
__global__ __launch_bounds__(256) void k_core_partial(
    const float* __restrict__ a0, const float* __restrict__ a1,
    const float* __restrict__ a2, const float* __restrict__ a3,
    float* __restrict__ partial) {
  const float* p = blockIdx.y == 0 ? a0 : blockIdx.y == 1 ? a1
                 : blockIdx.y == 2 ? a2 : a3;
  const float4* p4 = (const float4*)p;
  float s = 0.f;
  int base = blockIdx.x * 4096 + threadIdx.x;
  #pragma unroll
  for (int i = 0; i < 16; ++i) {
    float4 v = p4[base + i * 256];
    s += (v.x + v.y) + (v.z + v.w);
  }
  __shared__ float red[256];
  red[threadIdx.x] = s;
  __syncthreads();
  for (int off = 128; off; off >>= 1) {
    if (threadIdx.x < off) red[threadIdx.x] += red[threadIdx.x + off];
    __syncthreads();
  }
  if (threadIdx.x == 0) partial[blockIdx.y * 64 + blockIdx.x] = red[0];
}

__global__ void k_core_final(const float* __restrict__ partial,
                             float* __restrict__ S) {
  int t = threadIdx.x;
  if (t < 4) {
    float s = 0.f;
    for (int j = 0; j < 64; ++j) s += partial[t * 64 + j];
    S[t] = s;
  }
}

// ---------------- forward H+W DFT: x(b,c,z,:,:) -> A2[plane][t] ------------
__global__ __launch_bounds__(256) void k_fwd_wh(const float* __restrict__ x,
                                                float2* __restrict__ A2) {
  __shared__ float2 T[4][64][17];   // [w][hf], pad 17
  int wave = threadIdx.x >> 6, lane = threadIdx.x & 63;
  int plane = blockIdx.x * 4 + wave;            // (b*64+c)*64+z
  const float* xp = x + (size_t)plane * 4096 + lane;   // lane = w
  // stage 1: col[hf] = sum_h x[h][w] e^{-2pi i h hf/64}, literal twiddles
  float cre[16], cim[16];
  {
    float x0 = xp[0], x32 = xp[32 * 64];
    #pragma unroll
    for (int hf = 0; hf < 16; ++hf) {
      cre[hf] = x0 + ((hf & 1) ? -x32 : x32);
      cim[hf] = 0.f;
    }
  }
  #pragma unroll
  for (int h = 1; h < 32; ++h) {
    float va = xp[h * 64], vb = xp[(64 - h) * 64];
    float u = va + vb, d = va - vb;
    #pragma unroll
    for (int hf = 0; hf < 16; ++hf) {
      cre[hf] = fmaf(u, cos64f(h * hf), cre[hf]);
      cim[hf] = fmaf(d, -sin64f(h * hf), cim[hf]);
    }
  }
  #pragma unroll
  for (int hf = 0; hf < 16; ++hf)
    T[wave][lane][hf] = make_float2(cre[hf], cim[hf]);
  __syncthreads();
  // stage 2 (paired): A[hf][wf] = sum_w T[w][hf] e^{-2pi i w wf/64}
  int hf = lane & 15, wq = lane >> 4;
  float2 rot[4], CS[4], acc[4];
  float2 T0 = T[wave][0][hf], T32 = T[wave][32][hf];
  #pragma unroll
  for (int j = 0; j < 4; ++j) {
    int wf = wq + 4 * j;
    float s, c;
    sincosf((TWOPI / 64.f) * (float)wf, &s, &c);
    rot[j] = make_float2(c, s);
    CS[j] = make_float2(c, s);        // value at w=1
    float sgn = (wf & 1) ? -1.f : 1.f;
    acc[j] = make_float2(T0.x + sgn * T32.x, T0.y + sgn * T32.y);
  }
  #pragma unroll 4
  for (int w = 1; w < 32; ++w) {
    float2 a = T[wave][w][hf], b2 = T[wave][64 - w][hf];
    float Sr = a.x + b2.x, Si = a.y + b2.y;
    float Dr = a.x - b2.x, Di = a.y - b2.y;
    #pragma unroll
    for (int j = 0; j < 4; ++j) {
      float C = CS[j].x, Sn = CS[j].y;
      acc[j].x = fmaf(Sr, C, fmaf(Di, Sn, acc[j].x));
      acc[j].y = fmaf(Si, C, fmaf(-Dr, Sn, acc[j].y));
      float nC = C * rot[j].x - Sn * rot[j].y;
      CS[j].y = fmaf(C, rot[j].y, Sn * rot[j].x);
      CS[j].x = nC;
    }
  }
  float2* dst = A2 + (size_t)plane * 256 + lane;   // t = j*64+lane
  #pragma unroll
  for (int j = 0; j < 4; ++j) dst[j * 64] = acc[j];
}

// ---------------- projection c -> r: P[b,r,z,t] = sum_c U_in[c,r] A2 -------
__global__ __launch_bounds__(256) void k_proj(const float2* __restrict__ A2,
                                              float2* __restrict__ P,
                                              const float* __restrict__ U_in) {
  __shared__ float sU[1024];
  int t = threadIdx.x;
  #pragma unroll
  for (int i = 0; i < 4; ++i) sU[t + 256 * i] = U_in[t + 256 * i];
  __syncthreads();
  int b = blockIdx.x >> 6, z = blockIdx.x & 63;
  const float2* src = A2 + (((size_t)b * 64) * 64 + z) * 256 + t;
  float2 acc[16];
  #pragma unroll
  for (int r = 0; r < 16; ++r) acc[r] = make_float2(0.f, 0.f);
  for (int c = 0; c < 64; ++c) {
    float2 v = src[(size_t)c * 16384];
    #pragma unroll
    for (int r = 0; r < 16; ++r) {
      float u = sU[c * 16 + r];
      acc[r].x = fmaf(v.x, u, acc[r].x);
      acc[r].y = fmaf(v.y, u, acc[r].y);
    }
  }
  float2* dst = P + (((size_t)b * 16) * 64 + z) * 256 + t;
  #pragma unroll
  for (int r = 0; r < 16; ++r) dst[(size_t)r * 16384] = acc[r];
}

// ---------------- forward Z DFT (r-space, literal paired twiddles) ---------
// P[br][z][t] -> Pf[br][zf32][t]; zf k: freq k (KOFF=0) or k+48 (KOFF=48)
template <int KOFF>
__device__ __forceinline__ void fwd_z_body(const float2* __restrict__ src,
                                           float2* __restrict__ dst) {
  float2 acc[16];
  {
    float2 v0 = src[0], v32 = src[32 * 256];
    #pragma unroll
    for (int k = 0; k < 16; ++k) {
      float sgn = ((k + KOFF) & 1) ? -1.f : 1.f;
      acc[k] = make_float2(v0.x + sgn * v32.x, v0.y + sgn * v32.y);
    }
  }
  #pragma unroll
  for (int z = 1; z < 32; ++z) {
    float2 a = src[z * 256], b = src[(64 - z) * 256];
    float Sr = a.x + b.x, Si = a.y + b.y;
    float Dr = a.x - b.x, Di = a.y - b.y;
    #pragma unroll
    for (int k = 0; k < 16; ++k) {
      const float c = cos64f(z * (k + KOFF));
      const float s = sin64f(z * (k + KOFF));
      acc[k].x = fmaf(Sr, c, fmaf(Di, s, acc[k].x));
      acc[k].y = fmaf(Si, c, fmaf(-Dr, s, acc[k].y));
    }
  }
  #pragma unroll
  for (int k = 0; k < 16; ++k) dst[k * 256] = acc[k];
}

__global__ __launch_bounds__(256) void k_fwd_z2(const float2* __restrict__ P,
                                                float2* __restrict__ Pf) {
  int br = blockIdx.x, t = threadIdx.x;
  const float2* src = P + (size_t)br * 16384 + t;
  float2* dst = Pf + (size_t)br * 8192 + (size_t)blockIdx.y * 4096 + t;
  if (blockIdx.y == 0) fwd_z_body<0>(src, dst);
  else                 fwd_z_body<48>(src, dst);
}

// ---------------- mode scale + inverse Z (r-space, literal paired) ---------
// Q[br][z][t] = sum_k F[k]*Pf[br][k][t] * e^{+2pi i z f(k)/64}, f(k)=k|k+32
template <int HALF>
__device__ __forceinline__ void inv_z_body(const float* __restrict__ gr,
                                           const float* __restrict__ gi,
                                           float2* __restrict__ dst) {
  if (HALF == 0) {
    {  // z = 0
      float sr = 0.f, si = 0.f;
      #pragma unroll
      for (int k = 0; k < 32; ++k) { sr += gr[k]; si += gi[k]; }
      dst[0] = make_float2(sr, si);
    }
    #pragma unroll
    for (int z = 1; z <= 16; ++z) {
      float Ar = 0.f, Ai = 0.f, Br = 0.f, Bi = 0.f;
      #pragma unroll
      for (int k = 0; k < 32; ++k) {
        const int f = (k < 16) ? k : (k + 32);
        const float c = cos64f(z * f), s = sin64f(z * f);
        Ar = fmaf(gr[k], c, Ar); Ai = fmaf(gi[k], c, Ai);
        Br = fmaf(gr[k], s, Br); Bi = fmaf(gi[k], s, Bi);
      }
      dst[z * 256] = make_float2(Ar - Bi, Ai + Br);
      dst[(64 - z) * 256] = make_float2(Ar + Bi, Ai - Br);
    }
  } else {
    {  // z = 32
      float sr = 0.f, si = 0.f;
      #pragma unroll
      for (int k = 0; k < 32; ++k) {
        if (k & 1) { sr -= gr[k]; si -= gi[k]; }
        else       { sr += gr[k]; si += gi[k]; }
      }
      dst[32 * 256] = make_float2(sr, si);
    }
    #pragma unroll
    for (int z = 17; z < 32; ++z) {
      float Ar = 0.f, Ai = 0.f, Br = 0.f, Bi = 0.f;
      #pragma unroll
      for (int k = 0; k < 32; ++k) {
        const int f = (k < 16) ? k : (k + 32);
        const float c = cos64f(z * f), s = sin64f(z * f);
        Ar = fmaf(gr[k], c, Ar); Ai = fmaf(gi[k], c, Ai);
        Br = fmaf(gr[k], s, Br); Bi = fmaf(gi[k], s, Bi);
      }
      dst[z * 256] = make_float2(Ar - Bi, Ai + Br);
      dst[(64 - z) * 256] = make_float2(Ar + Bi, Ai - Br);
    }
  }
}

__global__ __launch_bounds__(256) void k_scale_inv_z(
    const float2* __restrict__ Pf, float2* __restrict__ Q,
    const float* __restrict__ U_z, const float* __restrict__ U_h,
    const float* __restrict__ U_w, const float* __restrict__ U_z2,
    const float* __restrict__ U_h2, const float* __restrict__ S4) {
  int br = blockIdx.x, r = br & 15, t = threadIdx.x;
  int hf = t & 15, wf = ((t >> 4) & 3) + 4 * (t >> 6);
  const float2* src = Pf + (size_t)br * 8192 + t;
  const float invN = 1.0f / 262144.0f;
  float S1r = S4[0] * invN, S1i = S4[1] * invN;
  float S2r = S4[2] * invN, S2i = S4[3] * invN;
  float cw = U_w[hf * 16 + r];
  float ch1 = U_h[wf * 16 + r] * cw, ch2 = U_h2[wf * 16 + r] * cw;
  float gr[32], gi[32];
  #pragma unroll
  for (int k = 0; k < 16; ++k) {
    float2 v = src[k * 256];
    float g = U_z[k * 16 + r] * ch1;
    float Fr = S1r * g, Fi = S1i * g;
    gr[k] = v.x * Fr - v.y * Fi;
    gi[k] = v.x * Fi + v.y * Fr;
  }
  #pragma unroll
  for (int k = 0; k < 16; ++k) {
    float2 v = src[(k + 16) * 256];
    float g = U_z2[k * 16 + r] * ch2;
    float Fr = S2r * g, Fi = S2i * g;
    gr[k + 16] = v.x * Fr - v.y * Fi;
    gi[k + 16] = v.x * Fi + v.y * Fr;
  }
  float2* dst = Q + (size_t)br * 16384 + t;
  if (blockIdx.y == 0) inv_z_body<0>(gr, gi, dst);
  else                 inv_z_body<1>(gr, gi, dst);
}

// ---------------- expansion r -> o: Bz[b,o,z,t] = sum_r U_out[o,r] Q -------
__global__ __launch_bounds__(256) void k_expand_o(const float2* __restrict__ Q,
                                                  float2* __restrict__ Bz,
                                                  const float* __restrict__ U_out) {
  __shared__ float sU[1024];
  int t = threadIdx.x;
  #pragma unroll
  for (int i = 0; i < 4; ++i) sU[t + 256 * i] = U_out[t + 256 * i];
  __syncthreads();
  int b = blockIdx.x >> 6, z = blockIdx.x & 63;
  const float2* src = Q + (((size_t)b * 16) * 64 + z) * 256 + t;
  float2 q[16];
  #pragma unroll
  for (int r = 0; r < 16; ++r) q[r] = src[(size_t)r * 16384];
  float2* dst = Bz + (((size_t)b * 64) * 64 + z) * 256 + t;
  for (int o = 0; o < 64; ++o) {
    float re = 0.f, im = 0.f;
    #pragma unroll
    for (int r = 0; r < 16; ++r) {
      float u = sU[o * 16 + r];
      re = fmaf(q[r].x, u, re);
      im = fmaf(q[r].y, u, im);
    }
    dst[(size_t)o * 16384] = make_float2(re, im);
  }
}

// ---------------- inverse H + real inverse W: Bz plane -> out plane --------
__global__ __launch_bounds__(256) void k_inv_hw(const float2* __restrict__ Bz,
                                                float* __restrict__ out) {
  __shared__ float2 GL[4][256];
  int wave = threadIdx.x >> 6, lane = threadIdx.x & 63;
  int plane = blockIdx.x * 4 + wave;            // (b*64+o)*64+z
  const float4* p4 = (const float4*)(Bz + (size_t)plane * 256);
  #pragma unroll
  for (int half = 0; half < 2; ++half) {
    float4 v = p4[lane + 64 * half];
    int t0 = 2 * (lane + 64 * half);
    int h0 = t0 & 15, w0 = ((t0 >> 4) & 3) + 4 * (t0 >> 6);
    int t1 = t0 + 1;
    int h1 = t1 & 15, w1 = ((t1 >> 4) & 3) + 4 * (t1 >> 6);
    GL[wave][h0 * 16 + w0] = make_float2(v.x, v.y);
    GL[wave][h1 * 16 + w1] = make_float2(v.z, v.w);
  }
  __syncthreads();
  float2 E2[16];   // 2 e^{+2pi i w wf/64}, w = lane
  {
    float s, c;
    sincosf((TWOPI / 64.f) * (float)lane, &s, &c);
    float2 E = make_float2(c, s);
    float2 St = E;
    #pragma unroll
    for (int wf = 1; wf < 16; ++wf) {
      E2[wf] = make_float2(E.x + E.x, E.y + E.y);
      float ex = E.x * St.x - E.y * St.y;
      E.y = fmaf(E.x, St.y, E.y * St.x);
      E.x = ex;
    }
  }
  float qre[16], qim[16];
  #pragma unroll
  for (int hf = 0; hf < 16; ++hf) {
    const float2* gp = &GL[wave][hf * 16];
    float2 g0 = gp[0], g1 = gp[1];
    float ar = g0.x + (g1.x * E2[1].x - g1.y * E2[1].y);
    float ai = g0.y + (g1.x * E2[1].y + g1.y * E2[1].x);
    #pragma unroll
    for (int wf = 2; wf < 16; ++wf) {
      float2 gv = gp[wf];
      ar = fmaf(gv.x, E2[wf].x, fmaf(-gv.y, E2[wf].y, ar));
      ai = fmaf(gv.x, E2[wf].y, fmaf(gv.y, E2[wf].x, ai));
    }
    qre[hf] = ar; qim[hf] = ai;
  }
  float* op = out + (size_t)plane * 4096 + lane;
  {
    float P = qre[0];
    #pragma unroll
    for (int hf = 1; hf < 16; ++hf) P += qre[hf];
    op[0] = P;
  }
  {
    float P = qre[0];
    #pragma unroll
    for (int hf = 1; hf < 16; ++hf) P += (hf & 1) ? -qre[hf] : qre[hf];
    op[32 * 64] = P;
  }
  #pragma unroll
  for (int h = 1; h < 32; ++h) {
    float P = qre[0], Q = 0.f;
    #pragma unroll
    for (int hf = 1; hf < 16; ++hf) {
      P = fmaf(qre[hf], cos64f(h * hf), P);
      Q = fmaf(qim[hf], sin64f(h * hf), Q);
    }
    op[h * 64] = P - Q;
    op[(64 - h) * 64] = P + Q;
  }
}

extern "C" void kernel_launch(void* const* d_in, const int* in_sizes, int n_in,
                              void* d_out, int out_size, void* d_ws,
                              size_t ws_size, hipStream_t stream) {
  const float* x    = (const float*)d_in[0];
  const float* Uin  = (const float*)d_in[1];
  const float* Uout = (const float*)d_in[2];
  const float* Uz   = (const float*)d_in[3];
  const float* Uh   = (const float*)d_in[4];
  const float* Uw   = (const float*)d_in[5];
  const float* Uz2  = (const float*)d_in[6];
  const float* Uh2  = (const float*)d_in[7];
  const float* cr   = (const float*)d_in[8];
  const float* ci   = (const float*)d_in[9];
  const float* c2r  = (const float*)d_in[10];
  const float* c2i  = (const float*)d_in[11];
  float* outp = (float*)d_out;

  char* ws = (char*)d_ws;
  float* S       = (float*)ws;            // 4 floats
  float* partial = (float*)(ws + 256);    // 256 floats
  float2* A2 = (float2*)(ws + 4096);                 // 33,554,432 B
  float2* P  = (float2*)(ws + 33558528);             //  8,388,608 B
  float2* Pf = (float2*)(ws + 41947136);             //  8,388,608 B
  float2* Q  = (float2*)(ws + 50335744);             // 16,777,216 B
  float2* Bz = A2;   // A2 dead after k_proj; reuse for expanded o-space

  k_core_partial<<<dim3(64, 4), 256, 0, stream>>>(cr, ci, c2r, c2i, partial);
  k_core_final<<<1, 64, 0, stream>>>(partial, S);
  k_fwd_wh<<<4096, 256, 0, stream>>>(x, A2);
  k_proj<<<256, 256, 0, stream>>>(A2, P, Uin);
  k_fwd_z2<<<dim3(64, 2), 256, 0, stream>>>(P, Pf);
  k_scale_inv_z<<<dim3(64, 2), 256, 0, stream>>>(Pf, Q, Uz, Uh, Uw, Uz2, Uh2,
                                                 S);
  k_expand_o<<<256, 256, 0, stream>>>(Q, Bz, Uout);
  k_inv_hw<<<4096, 256, 0, stream>>>(Bz, outp);
}

// Round 4
// 194.359 us; speedup vs baseline: 4.4599x; 1.0614x over previous
//
#include <hip/hip_runtime.h>

// Problem constants: B=4, C=64, Z=H=W=64, modes 16, rank 16.
#define TWOPI 6.28318530717958647692f

// cos/sin(2*pi*k/64) as constexpr (compile-time literals after full unroll)
constexpr float COSQ[17] = {
  1.0f, 0.995184727f, 0.980785280f, 0.956940336f, 0.923879533f,
  0.881921264f, 0.831469612f, 0.773010453f, 0.707106781f,
  0.634393284f, 0.555570233f, 0.471396737f, 0.382683432f,
  0.290284677f, 0.195090322f, 0.098017140f, 0.0f
};
__host__ __device__ constexpr float cos64f(int k) {
  k &= 63;
  return (k <= 16) ? COSQ[k] : (k < 32) ? -COSQ[32 - k]
       : (k <= 48) ? -COSQ[k - 32] : COSQ[64 - k];
}
__host__ __device__ constexpr float sin64f(int k) { return cos64f(k + 48); }

// t-layout of the 256 (hf,wf) pairs:  t = j*64 + wq*16 + hf, wf = wq+4j.
// decode: hf = t&15, wf = ((t>>4)&3) + 4*(t>>6); encode: t(hf,wf) =
// (wf>>2)*64 + (wf&3)*16 + hf.

// ---------------- core partial sums ----------------------------------------
__global__ __launch_bounds__(256) void k_core_partial(
    const float* __restrict__ a0, const float* __restrict__ a1,
    const float* __restrict__ a2, const float* __restrict__ a3,
    float* __restrict__ partial) {
  const float* p = blockIdx.y == 0 ? a0 : blockIdx.y == 1 ? a1
                 : blockIdx.y == 2 ? a2 : a3;
  const float4* p4 = (const float4*)p;
  float s = 0.f;
  int base = blockIdx.x * 4096 + threadIdx.x;
  #pragma unroll
  for (int i = 0; i < 16; ++i) {
    float4 v = p4[base + i * 256];
    s += (v.x + v.y) + (v.z + v.w);
  }
  __shared__ float red[256];
  red[threadIdx.x] = s;
  __syncthreads();
  for (int off = 128; off; off >>= 1) {
    if (threadIdx.x < off) red[threadIdx.x] += red[threadIdx.x + off];
    __syncthreads();
  }
  if (threadIdx.x == 0) partial[blockIdx.y * 64 + blockIdx.x] = red[0];
}

// ---------------- forward H+W DFT: x(b,c,z,:,:) -> A2[plane][t] ------------
__global__ __launch_bounds__(256) void k_fwd_wh(const float* __restrict__ x,
                                                float2* __restrict__ A2) {
  __shared__ float2 T[4][64][17];   // [w][hf], pad 17
  int wave = threadIdx.x >> 6, lane = threadIdx.x & 63;
  int plane = blockIdx.x * 4 + wave;            // (b*64+c)*64+z
  const float* xp = x + (size_t)plane * 4096 + lane;   // lane = w
  // stage 1: col[hf] = sum_h x[h][w] e^{-2pi i h hf/64}, literal twiddles
  float cre[16], cim[16];
  {
    float x0 = xp[0], x32 = xp[32 * 64];
    #pragma unroll
    for (int hf = 0; hf < 16; ++hf) {
      cre[hf] = x0 + ((hf & 1) ? -x32 : x32);
      cim[hf] = 0.f;
    }
  }
  #pragma unroll
  for (int h = 1; h < 32; ++h) {
    float va = xp[h * 64], vb = xp[(64 - h) * 64];
    float u = va + vb, d = va - vb;
    #pragma unroll
    for (int hf = 0; hf < 16; ++hf) {
      cre[hf] = fmaf(u, cos64f(h * hf), cre[hf]);
      cim[hf] = fmaf(d, -sin64f(h * hf), cim[hf]);
    }
  }
  #pragma unroll
  for (int hf = 0; hf < 16; ++hf)
    T[wave][lane][hf] = make_float2(cre[hf], cim[hf]);
  __syncthreads();
  // stage 2 (paired): A[hf][wf] = sum_w T[w][hf] e^{-2pi i w wf/64}
  int hf = lane & 15, wq = lane >> 4;
  float2 rot[4], CS[4], acc[4];
  float2 T0 = T[wave][0][hf], T32 = T[wave][32][hf];
  #pragma unroll
  for (int j = 0; j < 4; ++j) {
    int wf = wq + 4 * j;
    float s, c;
    sincosf((TWOPI / 64.f) * (float)wf, &s, &c);
    rot[j] = make_float2(c, s);
    CS[j] = make_float2(c, s);        // value at w=1
    float sgn = (wf & 1) ? -1.f : 1.f;
    acc[j] = make_float2(T0.x + sgn * T32.x, T0.y + sgn * T32.y);
  }
  #pragma unroll 4
  for (int w = 1; w < 32; ++w) {
    float2 a = T[wave][w][hf], b2 = T[wave][64 - w][hf];
    float Sr = a.x + b2.x, Si = a.y + b2.y;
    float Dr = a.x - b2.x, Di = a.y - b2.y;
    #pragma unroll
    for (int j = 0; j < 4; ++j) {
      float C = CS[j].x, Sn = CS[j].y;
      acc[j].x = fmaf(Sr, C, fmaf(Di, Sn, acc[j].x));
      acc[j].y = fmaf(Si, C, fmaf(-Dr, Sn, acc[j].y));
      float nC = C * rot[j].x - Sn * rot[j].y;
      CS[j].y = fmaf(C, rot[j].y, Sn * rot[j].x);
      CS[j].x = nC;
    }
  }
  float2* dst = A2 + (size_t)plane * 256 + lane;   // t = j*64+lane
  #pragma unroll
  for (int j = 0; j < 4; ++j) dst[j * 64] = acc[j];
}

// ---------------- projection c -> r (+ fused core-final sum) ---------------
__global__ __launch_bounds__(256) void k_proj(const float2* __restrict__ A2,
                                              float2* __restrict__ P,
                                              const float* __restrict__ U_in,
                                              const float* __restrict__ partial,
                                              float* __restrict__ S) {
  if (blockIdx.x == 0 && threadIdx.x < 4) {
    float s = 0.f;
    for (int j = 0; j < 64; ++j) s += partial[threadIdx.x * 64 + j];
    S[threadIdx.x] = s;
  }
  __shared__ float sU[1024];
  int t = threadIdx.x;
  #pragma unroll
  for (int i = 0; i < 4; ++i) sU[t + 256 * i] = U_in[t + 256 * i];
  __syncthreads();
  int b = blockIdx.x >> 6, z = blockIdx.x & 63;
  const float2* src = A2 + (((size_t)b * 64) * 64 + z) * 256 + t;
  float2 acc[16];
  #pragma unroll
  for (int r = 0; r < 16; ++r) acc[r] = make_float2(0.f, 0.f);
  for (int c = 0; c < 64; ++c) {
    float2 v = src[(size_t)c * 16384];
    #pragma unroll
    for (int r = 0; r < 16; ++r) {
      float u = sU[c * 16 + r];
      acc[r].x = fmaf(v.x, u, acc[r].x);
      acc[r].y = fmaf(v.y, u, acc[r].y);
    }
  }
  float2* dst = P + (((size_t)b * 16) * 64 + z) * 256 + t;
  #pragma unroll
  for (int r = 0; r < 16; ++r) dst[(size_t)r * 16384] = acc[r];
}

// ---------------- fused z-chain: P -> (fwd z) -> scale -> (inv z) -> Q -----
// slot k<16: freq k; slot 16+k: freq 48+k. All twiddles literal.
template <int HALF>
__device__ __forceinline__ void inv_z_body(const float* __restrict__ gr,
                                           const float* __restrict__ gi,
                                           float2* __restrict__ dst) {
  if (HALF == 0) {
    {  // z = 0
      float sr = 0.f, si = 0.f;
      #pragma unroll
      for (int k = 0; k < 32; ++k) { sr += gr[k]; si += gi[k]; }
      dst[0] = make_float2(sr, si);
    }
    #pragma unroll
    for (int z = 1; z <= 16; ++z) {
      float Ar = 0.f, Ai = 0.f, Br = 0.f, Bi = 0.f;
      #pragma unroll
      for (int k = 0; k < 32; ++k) {
        const int f = (k < 16) ? k : (k + 32);
        const float c = cos64f(z * f), s = sin64f(z * f);
        Ar = fmaf(gr[k], c, Ar); Ai = fmaf(gi[k], c, Ai);
        Br = fmaf(gr[k], s, Br); Bi = fmaf(gi[k], s, Bi);
      }
      dst[z * 256] = make_float2(Ar - Bi, Ai + Br);
      dst[(64 - z) * 256] = make_float2(Ar + Bi, Ai - Br);
    }
  } else {
    {  // z = 32
      float sr = 0.f, si = 0.f;
      #pragma unroll
      for (int k = 0; k < 32; ++k) {
        if (k & 1) { sr -= gr[k]; si -= gi[k]; }
        else       { sr += gr[k]; si += gi[k]; }
      }
      dst[32 * 256] = make_float2(sr, si);
    }
    #pragma unroll
    for (int z = 17; z < 32; ++z) {
      float Ar = 0.f, Ai = 0.f, Br = 0.f, Bi = 0.f;
      #pragma unroll
      for (int k = 0; k < 32; ++k) {
        const int f = (k < 16) ? k : (k + 32);
        const float c = cos64f(z * f), s = sin64f(z * f);
        Ar = fmaf(gr[k], c, Ar); Ai = fmaf(gi[k], c, Ai);
        Br = fmaf(gr[k], s, Br); Bi = fmaf(gi[k], s, Bi);
      }
      dst[z * 256] = make_float2(Ar - Bi, Ai + Br);
      dst[(64 - z) * 256] = make_float2(Ar + Bi, Ai - Br);
    }
  }
}

__global__ __launch_bounds__(256) void k_zmix(
    const float2* __restrict__ P, float2* __restrict__ Q,
    const float* __restrict__ U_z, const float* __restrict__ U_h,
    const float* __restrict__ U_w, const float* __restrict__ U_z2,
    const float* __restrict__ U_h2, const float* __restrict__ S4) {
  int br = blockIdx.x, r = br & 15, t = threadIdx.x;
  int hf = t & 15, wf = ((t >> 4) & 3) + 4 * (t >> 6);
  const float2* src = P + (size_t)br * 16384 + t;
  // forward z (paired, literal): acc[k] = slot-k coefficient
  float2 acc[32];
  {
    float2 v0 = src[0], v32 = src[32 * 256];
    #pragma unroll
    for (int k = 0; k < 16; ++k) {
      float sgn = (k & 1) ? -1.f : 1.f;   // (-1)^k == (-1)^(48+k)
      float2 e = make_float2(v0.x + sgn * v32.x, v0.y + sgn * v32.y);
      acc[k] = e;
      acc[k + 16] = e;
    }
  }
  #pragma unroll
  for (int z = 1; z < 32; ++z) {
    float2 a = src[z * 256], b = src[(64 - z) * 256];
    float Sr = a.x + b.x, Si = a.y + b.y;
    float Dr = a.x - b.x, Di = a.y - b.y;
    #pragma unroll
    for (int k = 0; k < 16; ++k) {
      {
        const float c = cos64f(z * k), s = sin64f(z * k);
        acc[k].x = fmaf(Sr, c, fmaf(Di, s, acc[k].x));
        acc[k].y = fmaf(Si, c, fmaf(-Dr, s, acc[k].y));
      }
      {
        const float c = cos64f(z * (k + 48)), s = sin64f(z * (k + 48));
        acc[k + 16].x = fmaf(Sr, c, fmaf(Di, s, acc[k + 16].x));
        acc[k + 16].y = fmaf(Si, c, fmaf(-Dr, s, acc[k + 16].y));
      }
    }
  }
  // mode scale
  const float invN = 1.0f / 262144.0f;
  float S1r = S4[0] * invN, S1i = S4[1] * invN;
  float S2r = S4[2] * invN, S2i = S4[3] * invN;
  float cw = U_w[hf * 16 + r];
  float ch1 = U_h[wf * 16 + r] * cw, ch2 = U_h2[wf * 16 + r] * cw;
  float gr[32], gi[32];
  #pragma unroll
  for (int k = 0; k < 16; ++k) {
    float2 v = acc[k];
    float g = U_z[k * 16 + r] * ch1;
    float Fr = S1r * g, Fi = S1i * g;
    gr[k] = v.x * Fr - v.y * Fi;
    gi[k] = v.x * Fi + v.y * Fr;
  }
  #pragma unroll
  for (int k = 0; k < 16; ++k) {
    float2 v = acc[k + 16];
    float g = U_z2[k * 16 + r] * ch2;
    float Fr = S2r * g, Fi = S2i * g;
    gr[k + 16] = v.x * Fr - v.y * Fi;
    gi[k + 16] = v.x * Fi + v.y * Fr;
  }
  float2* dst = Q + (size_t)br * 16384 + t;
  if (blockIdx.y == 0) inv_z_body<0>(gr, gi, dst);
  else                 inv_z_body<1>(gr, gi, dst);
}

// ---------------- fused o-expand + inverse H + real inverse W --------------
// grid (b*64+z, og); block 256. Wave expands its own o into private LDS tile
// (same-wave producer/consumer: no barrier), then literal-twiddle iH + c2r-W.
__global__ __launch_bounds__(256) void k_inv_hw_ex(
    const float2* __restrict__ Q, float* __restrict__ out,
    const float* __restrict__ U_out) {
  __shared__ float2 sQ[16][256];
  __shared__ float2 GLo[4][256];
  __shared__ float sU[1024];
  int t = threadIdx.x;
  int b = blockIdx.x >> 6, z = blockIdx.x & 63, og = blockIdx.y;
  #pragma unroll
  for (int i = 0; i < 4; ++i) sU[t + 256 * i] = U_out[t + 256 * i];
  #pragma unroll
  for (int r = 0; r < 16; ++r)
    sQ[r][t] = Q[((size_t)(b * 16 + r) * 64 + z) * 256 + t];
  __syncthreads();
  int wave = t >> 6, lane = t & 63;
  // E2[wf] = 2 e^{+2pi i w wf/64}, w = lane (hoisted across o-loop)
  float2 E2[16];
  {
    float s, c;
    sincosf((TWOPI / 64.f) * (float)lane, &s, &c);
    float2 E = make_float2(c, s);
    float2 St = E;
    #pragma unroll
    for (int wfi = 1; wfi < 16; ++wfi) {
      E2[wfi] = make_float2(E.x + E.x, E.y + E.y);
      float ex = E.x * St.x - E.y * St.y;
      E.y = fmaf(E.x, St.y, E.y * St.x);
      E.x = ex;
    }
  }
  for (int oi = 0; oi < 8; ++oi) {
    int o = og * 32 + wave * 8 + oi;
    // expand rank-16 -> channel o into this wave's LDS tile (t-layout)
    #pragma unroll
    for (int q = 0; q < 4; ++q) {
      int tt = lane + 64 * q;
      float re = 0.f, im = 0.f;
      #pragma unroll
      for (int r = 0; r < 16; ++r) {
        float u = sU[o * 16 + r];
        float2 v = sQ[r][tt];
        re = fmaf(v.x, u, re);
        im = fmaf(v.y, u, im);
      }
      GLo[wave][tt] = make_float2(re, im);
    }
    // w-combine: q[hf] = GLo[t(hf,0)] + sum_{wf>=1} GLo[t(hf,wf)]*E2[wf]
    float qre[16], qim[16];
    #pragma unroll
    for (int hfi = 0; hfi < 16; ++hfi) {
      float2 g0 = GLo[wave][hfi];     // t(hf,0) = hf
      float ar = g0.x, ai = g0.y;
      #pragma unroll
      for (int wfi = 1; wfi < 16; ++wfi) {
        float2 gv = GLo[wave][(wfi >> 2) * 64 + (wfi & 3) * 16 + hfi];
        ar = fmaf(gv.x, E2[wfi].x, fmaf(-gv.y, E2[wfi].y, ar));
        ai = fmaf(gv.x, E2[wfi].y, fmaf(gv.y, E2[wfi].x, ai));
      }
      qre[hfi] = ar; qim[hfi] = ai;
    }
    // h-inverse (literal twiddles, h/64-h pairing), coalesced stores
    float* op = out + (((size_t)(b * 64 + o) * 64 + z)) * 4096 + lane;
    {
      float Pv = qre[0];
      #pragma unroll
      for (int hfi = 1; hfi < 16; ++hfi) Pv += qre[hfi];
      op[0] = Pv;
    }
    {
      float Pv = qre[0];
      #pragma unroll
      for (int hfi = 1; hfi < 16; ++hfi)
        Pv += (hfi & 1) ? -qre[hfi] : qre[hfi];
      op[32 * 64] = Pv;
    }
    #pragma unroll
    for (int h = 1; h < 32; ++h) {
      float Pv = qre[0], Qv = 0.f;
      #pragma unroll
      for (int hfi = 1; hfi < 16; ++hfi) {
        Pv = fmaf(qre[hfi], cos64f(h * hfi), Pv);
        Qv = fmaf(qim[hfi], sin64f(h * hfi), Qv);
      }
      op[h * 64] = Pv - Qv;
      op[(64 - h) * 64] = Pv + Qv;
    }
  }
}

extern "C" void kernel_launch(void* const* d_in, const int* in_sizes, int n_in,
                              void* d_out, int out_size, void* d_ws,
                              size_t ws_size, hipStream_t stream) {
  const float* x    = (const float*)d_in[0];
  const float* Uin  = (const float*)d_in[1];
  const float* Uout = (const float*)d_in[2];
  const float* Uz   = (const float*)d_in[3];
  const float* Uh   = (const float*)d_in[4];
  const float* Uw   = (const float*)d_in[5];
  const float* Uz2  = (const float*)d_in[6];
  const float* Uh2  = (const float*)d_in[7];
  const float* cr   = (const float*)d_in[8];
  const float* ci   = (const float*)d_in[9];
  const float* c2r  = (const float*)d_in[10];
  const float* c2i  = (const float*)d_in[11];
  float* outp = (float*)d_out;

  char* ws = (char*)d_ws;
  float* S       = (float*)ws;            // 4 floats
  float* partial = (float*)(ws + 256);    // 256 floats
  float2* A2 = (float2*)(ws + 4096);                 // 33,554,432 B
  float2* P  = (float2*)(ws + 33558528);             //  8,388,608 B
  float2* Q  = (float2*)(ws + 41947136);             // 16,777,216 B

  k_core_partial<<<dim3(64, 4), 256, 0, stream>>>(cr, ci, c2r, c2i, partial);
  k_fwd_wh<<<4096, 256, 0, stream>>>(x, A2);
  k_proj<<<256, 256, 0, stream>>>(A2, P, Uin, partial, S);
  k_zmix<<<dim3(64, 2), 256, 0, stream>>>(P, Q, Uz, Uh, Uw, Uz2, Uh2, S);
  k_inv_hw_ex<<<dim3(256, 2), 256, 0, stream>>>(Q, outp, Uout);
}

// Round 5
// 190.969 us; speedup vs baseline: 4.5391x; 1.0178x over previous
//
#include <hip/hip_runtime.h>

// Problem constants: B=4, C=64, Z=H=W=64, modes 16, rank 16.
#define TWOPI 6.28318530717958647692f

// cos/sin(2*pi*k/64) as constexpr (compile-time literals after full unroll)
constexpr float COSQ[17] = {
  1.0f, 0.995184727f, 0.980785280f, 0.956940336f, 0.923879533f,
  0.881921264f, 0.831469612f, 0.773010453f, 0.707106781f,
  0.634393284f, 0.555570233f, 0.471396737f, 0.382683432f,
  0.290284677f, 0.195090322f, 0.098017140f, 0.0f
};
__host__ __device__ constexpr float cos64f(int k) {
  k &= 63;
  return (k <= 16) ? COSQ[k] : (k < 32) ? -COSQ[32 - k]
       : (k <= 48) ? -COSQ[k - 32] : COSQ[64 - k];
}
__host__ __device__ constexpr float sin64f(int k) { return cos64f(k + 48); }

// t-layout of the 256 (hf,wf) pairs:  t = j*64 + wq*16 + hf, wf = wq+4j.
// decode: hf = t&15, wf = ((t>>4)&3) + 4*(t>>6); encode: t(hf,wf) =
// (wf>>2)*64 + (wf&3)*16 + hf.

// ---------------- fused: core partial sums + forward H+W DFT ---------------
// blocks 0..255: core-tensor partial reduction (overlaps its 67 MB read with
// the DFT blocks). blocks 256..4351: one (b,c,z) plane per wave.
__global__ __launch_bounds__(256) void k_fwd_wh_core(
    const float* __restrict__ x, float2* __restrict__ A2,
    const float* __restrict__ a0, const float* __restrict__ a1,
    const float* __restrict__ a2, const float* __restrict__ a3,
    float* __restrict__ partial) {
  __shared__ float2 T[4][64][17];   // [w][hf], pad 17 (fwd branch)
  __shared__ float red[256];        // core branch
  if (blockIdx.x < 256) {
    int bx = blockIdx.x & 63, by = blockIdx.x >> 6;
    const float* p = by == 0 ? a0 : by == 1 ? a1 : by == 2 ? a2 : a3;
    const float4* p4 = (const float4*)p;
    float s = 0.f;
    int base = bx * 4096 + threadIdx.x;
    #pragma unroll
    for (int i = 0; i < 16; ++i) {
      float4 v = p4[base + i * 256];
      s += (v.x + v.y) + (v.z + v.w);
    }
    red[threadIdx.x] = s;
    __syncthreads();
    for (int off = 128; off; off >>= 1) {
      if (threadIdx.x < off) red[threadIdx.x] += red[threadIdx.x + off];
      __syncthreads();
    }
    if (threadIdx.x == 0) partial[by * 64 + bx] = red[0];
    return;
  }
  int wave = threadIdx.x >> 6, lane = threadIdx.x & 63;
  int plane = (blockIdx.x - 256) * 4 + wave;     // (b*64+c)*64+z
  const float* xp = x + (size_t)plane * 4096 + lane;   // lane = w
  // stage 1: col[hf] = sum_h x[h][w] e^{-2pi i h hf/64}, literal twiddles
  float cre[16], cim[16];
  {
    float x0 = xp[0], x32 = xp[32 * 64];
    #pragma unroll
    for (int hf = 0; hf < 16; ++hf) {
      cre[hf] = x0 + ((hf & 1) ? -x32 : x32);
      cim[hf] = 0.f;
    }
  }
  #pragma unroll
  for (int h = 1; h < 32; ++h) {
    float va = xp[h * 64], vb = xp[(64 - h) * 64];
    float u = va + vb, d = va - vb;
    #pragma unroll
    for (int hf = 0; hf < 16; ++hf) {
      cre[hf] = fmaf(u, cos64f(h * hf), cre[hf]);
      cim[hf] = fmaf(d, -sin64f(h * hf), cim[hf]);
    }
  }
  #pragma unroll
  for (int hf = 0; hf < 16; ++hf)
    T[wave][lane][hf] = make_float2(cre[hf], cim[hf]);
  __syncthreads();
  // stage 2 (paired): A[hf][wf] = sum_w T[w][hf] e^{-2pi i w wf/64}
  int hf = lane & 15, wq = lane >> 4;
  float2 rot[4], CS[4], acc[4];
  float2 T0 = T[wave][0][hf], T32 = T[wave][32][hf];
  #pragma unroll
  for (int j = 0; j < 4; ++j) {
    int wf = wq + 4 * j;
    float s, c;
    sincosf((TWOPI / 64.f) * (float)wf, &s, &c);
    rot[j] = make_float2(c, s);
    CS[j] = make_float2(c, s);        // value at w=1
    float sgn = (wf & 1) ? -1.f : 1.f;
    acc[j] = make_float2(T0.x + sgn * T32.x, T0.y + sgn * T32.y);
  }
  #pragma unroll 4
  for (int w = 1; w < 32; ++w) {
    float2 a = T[wave][w][hf], b2 = T[wave][64 - w][hf];
    float Sr = a.x + b2.x, Si = a.y + b2.y;
    float Dr = a.x - b2.x, Di = a.y - b2.y;
    #pragma unroll
    for (int j = 0; j < 4; ++j) {
      float C = CS[j].x, Sn = CS[j].y;
      acc[j].x = fmaf(Sr, C, fmaf(Di, Sn, acc[j].x));
      acc[j].y = fmaf(Si, C, fmaf(-Dr, Sn, acc[j].y));
      float nC = C * rot[j].x - Sn * rot[j].y;
      CS[j].y = fmaf(C, rot[j].y, Sn * rot[j].x);
      CS[j].x = nC;
    }
  }
  float2* dst = A2 + (size_t)plane * 256 + lane;   // t = j*64+lane
  #pragma unroll
  for (int j = 0; j < 4; ++j) dst[j * 64] = acc[j];
}

// ---------------- projection c -> r (+ fused core-final sum) ---------------
// grid (256 bz, 2 rg): each block computes 8 of the 16 ranks.
__global__ __launch_bounds__(256) void k_proj(const float2* __restrict__ A2,
                                              float2* __restrict__ P,
                                              const float* __restrict__ U_in,
                                              const float* __restrict__ partial,
                                              float* __restrict__ S) {
  if (blockIdx.x == 0 && blockIdx.y == 0 && threadIdx.x < 4) {
    float s = 0.f;
    for (int j = 0; j < 64; ++j) s += partial[threadIdx.x * 64 + j];
    S[threadIdx.x] = s;
  }
  __shared__ float sU[1024];
  int t = threadIdx.x;
  #pragma unroll
  for (int i = 0; i < 4; ++i) sU[t + 256 * i] = U_in[t + 256 * i];
  __syncthreads();
  int b = blockIdx.x >> 6, z = blockIdx.x & 63, r0 = blockIdx.y * 8;
  const float2* src = A2 + (((size_t)b * 64) * 64 + z) * 256 + t;
  float2 acc[8];
  #pragma unroll
  for (int r = 0; r < 8; ++r) acc[r] = make_float2(0.f, 0.f);
  for (int c = 0; c < 64; ++c) {
    float2 v = src[(size_t)c * 16384];
    #pragma unroll
    for (int r = 0; r < 8; ++r) {
      float u = sU[c * 16 + r0 + r];
      acc[r].x = fmaf(v.x, u, acc[r].x);
      acc[r].y = fmaf(v.y, u, acc[r].y);
    }
  }
  float2* dst = P + (((size_t)b * 16 + r0) * 64 + z) * 256 + t;
  #pragma unroll
  for (int r = 0; r < 8; ++r) dst[(size_t)r * 16384] = acc[r];
}

// ---------------- fused z-chain: P -> (fwd z) -> scale -> (inv z) -> Q -----
// slot k<16: freq k; slot 16+k: freq 48+k. All twiddles literal.
// Y splits the inverse-z output range into quarters.
template <int Y>
__device__ __forceinline__ void inv_z_q(const float* __restrict__ gr,
                                        const float* __restrict__ gi,
                                        float2* __restrict__ dst) {
  if (Y == 0) {   // z = 0
    float sr = 0.f, si = 0.f;
    #pragma unroll
    for (int k = 0; k < 32; ++k) { sr += gr[k]; si += gi[k]; }
    dst[0] = make_float2(sr, si);
  }
  if (Y == 2) {   // z = 32
    float sr = 0.f, si = 0.f;
    #pragma unroll
    for (int k = 0; k < 32; ++k) {
      if (k & 1) { sr -= gr[k]; si -= gi[k]; }
      else       { sr += gr[k]; si += gi[k]; }
    }
    dst[32 * 256] = make_float2(sr, si);
  }
  constexpr int z0 = (Y == 0) ? 1 : (Y == 1) ? 9 : (Y == 2) ? 17 : 25;
  constexpr int z1 = (Y == 0) ? 8 : (Y == 1) ? 16 : (Y == 2) ? 24 : 31;
  #pragma unroll
  for (int z = z0; z <= z1; ++z) {
    float Ar = 0.f, Ai = 0.f, Br = 0.f, Bi = 0.f;
    #pragma unroll
    for (int k = 0; k < 32; ++k) {
      const int f = (k < 16) ? k : (k + 32);
      const float c = cos64f(z * f), s = sin64f(z * f);
      Ar = fmaf(gr[k], c, Ar); Ai = fmaf(gi[k], c, Ai);
      Br = fmaf(gr[k], s, Br); Bi = fmaf(gi[k], s, Bi);
    }
    dst[z * 256] = make_float2(Ar - Bi, Ai + Br);
    dst[(64 - z) * 256] = make_float2(Ar + Bi, Ai - Br);
  }
}

__global__ __launch_bounds__(256) void k_zmix(
    const float2* __restrict__ P, float2* __restrict__ Q,
    const float* __restrict__ U_z, const float* __restrict__ U_h,
    const float* __restrict__ U_w, const float* __restrict__ U_z2,
    const float* __restrict__ U_h2, const float* __restrict__ S4) {
  int br = blockIdx.x, r = br & 15, t = threadIdx.x;
  int hf = t & 15, wf = ((t >> 4) & 3) + 4 * (t >> 6);
  const float2* src = P + (size_t)br * 16384 + t;
  // forward z (paired, literal): acc[k] = slot-k coefficient
  float2 acc[32];
  {
    float2 v0 = src[0], v32 = src[32 * 256];
    #pragma unroll
    for (int k = 0; k < 16; ++k) {
      float sgn = (k & 1) ? -1.f : 1.f;   // (-1)^k == (-1)^(48+k)
      float2 e = make_float2(v0.x + sgn * v32.x, v0.y + sgn * v32.y);
      acc[k] = e;
      acc[k + 16] = e;
    }
  }
  #pragma unroll
  for (int z = 1; z < 32; ++z) {
    float2 a = src[z * 256], b = src[(64 - z) * 256];
    float Sr = a.x + b.x, Si = a.y + b.y;
    float Dr = a.x - b.x, Di = a.y - b.y;
    #pragma unroll
    for (int k = 0; k < 16; ++k) {
      {
        const float c = cos64f(z * k), s = sin64f(z * k);
        acc[k].x = fmaf(Sr, c, fmaf(Di, s, acc[k].x));
        acc[k].y = fmaf(Si, c, fmaf(-Dr, s, acc[k].y));
      }
      {
        const float c = cos64f(z * (k + 48)), s = sin64f(z * (k + 48));
        acc[k + 16].x = fmaf(Sr, c, fmaf(Di, s, acc[k + 16].x));
        acc[k + 16].y = fmaf(Si, c, fmaf(-Dr, s, acc[k + 16].y));
      }
    }
  }
  // mode scale
  const float invN = 1.0f / 262144.0f;
  float S1r = S4[0] * invN, S1i = S4[1] * invN;
  float S2r = S4[2] * invN, S2i = S4[3] * invN;
  float cw = U_w[hf * 16 + r];
  float ch1 = U_h[wf * 16 + r] * cw, ch2 = U_h2[wf * 16 + r] * cw;
  float gr[32], gi[32];
  #pragma unroll
  for (int k = 0; k < 16; ++k) {
    float2 v = acc[k];
    float g = U_z[k * 16 + r] * ch1;
    float Fr = S1r * g, Fi = S1i * g;
    gr[k] = v.x * Fr - v.y * Fi;
    gi[k] = v.x * Fi + v.y * Fr;
  }
  #pragma unroll
  for (int k = 0; k < 16; ++k) {
    float2 v = acc[k + 16];
    float g = U_z2[k * 16 + r] * ch2;
    float Fr = S2r * g, Fi = S2i * g;
    gr[k + 16] = v.x * Fr - v.y * Fi;
    gi[k + 16] = v.x * Fi + v.y * Fr;
  }
  float2* dst = Q + (size_t)br * 16384 + t;
  switch (blockIdx.y) {
    case 0: inv_z_q<0>(gr, gi, dst); break;
    case 1: inv_z_q<1>(gr, gi, dst); break;
    case 2: inv_z_q<2>(gr, gi, dst); break;
    default: inv_z_q<3>(gr, gi, dst); break;
  }
}

// ---------------- fused o-expand + inverse H + real inverse W --------------
// grid (b*64+z, og=4); block 256. Wave expands its own o into private LDS
// tile (same-wave producer/consumer: no barrier), then literal iH + c2r-W.
__global__ __launch_bounds__(256) void k_inv_hw_ex(
    const float2* __restrict__ Q, float* __restrict__ out,
    const float* __restrict__ U_out) {
  __shared__ float2 sQ[16][256];
  __shared__ float2 GLo[4][256];
  __shared__ float sU[1024];
  int t = threadIdx.x;
  int b = blockIdx.x >> 6, z = blockIdx.x & 63, og = blockIdx.y;
  #pragma unroll
  for (int i = 0; i < 4; ++i) sU[t + 256 * i] = U_out[t + 256 * i];
  #pragma unroll
  for (int r = 0; r < 16; ++r)
    sQ[r][t] = Q[((size_t)(b * 16 + r) * 64 + z) * 256 + t];
  __syncthreads();
  int wave = t >> 6, lane = t & 63;
  // E2[wf] = 2 e^{+2pi i w wf/64}, w = lane (hoisted across o-loop)
  float2 E2[16];
  {
    float s, c;
    sincosf((TWOPI / 64.f) * (float)lane, &s, &c);
    float2 E = make_float2(c, s);
    float2 St = E;
    #pragma unroll
    for (int wfi = 1; wfi < 16; ++wfi) {
      E2[wfi] = make_float2(E.x + E.x, E.y + E.y);
      float ex = E.x * St.x - E.y * St.y;
      E.y = fmaf(E.x, St.y, E.y * St.x);
      E.x = ex;
    }
  }
  for (int oi = 0; oi < 4; ++oi) {
    int o = og * 16 + wave * 4 + oi;
    // expand rank-16 -> channel o into this wave's LDS tile (t-layout)
    #pragma unroll
    for (int q = 0; q < 4; ++q) {
      int tt = lane + 64 * q;
      float re = 0.f, im = 0.f;
      #pragma unroll
      for (int r = 0; r < 16; ++r) {
        float u = sU[o * 16 + r];
        float2 v = sQ[r][tt];
        re = fmaf(v.x, u, re);
        im = fmaf(v.y, u, im);
      }
      GLo[wave][tt] = make_float2(re, im);
    }
    // w-combine: q[hf] = GLo[t(hf,0)] + sum_{wf>=1} GLo[t(hf,wf)]*E2[wf]
    float qre[16], qim[16];
    #pragma unroll
    for (int hfi = 0; hfi < 16; ++hfi) {
      float2 g0 = GLo[wave][hfi];     // t(hf,0) = hf
      float ar = g0.x, ai = g0.y;
      #pragma unroll
      for (int wfi = 1; wfi < 16; ++wfi) {
        float2 gv = GLo[wave][(wfi >> 2) * 64 + (wfi & 3) * 16 + hfi];
        ar = fmaf(gv.x, E2[wfi].x, fmaf(-gv.y, E2[wfi].y, ar));
        ai = fmaf(gv.x, E2[wfi].y, fmaf(gv.y, E2[wfi].x, ai));
      }
      qre[hfi] = ar; qim[hfi] = ai;
    }
    // h-inverse (literal twiddles, h/64-h pairing), coalesced stores
    float* op = out + (((size_t)(b * 64 + o) * 64 + z)) * 4096 + lane;
    {
      float Pv = qre[0];
      #pragma unroll
      for (int hfi = 1; hfi < 16; ++hfi) Pv += qre[hfi];
      op[0] = Pv;
    }
    {
      float Pv = qre[0];
      #pragma unroll
      for (int hfi = 1; hfi < 16; ++hfi)
        Pv += (hfi & 1) ? -qre[hfi] : qre[hfi];
      op[32 * 64] = Pv;
    }
    #pragma unroll
    for (int h = 1; h < 32; ++h) {
      float Pv = qre[0], Qv = 0.f;
      #pragma unroll
      for (int hfi = 1; hfi < 16; ++hfi) {
        Pv = fmaf(qre[hfi], cos64f(h * hfi), Pv);
        Qv = fmaf(qim[hfi], sin64f(h * hfi), Qv);
      }
      op[h * 64] = Pv - Qv;
      op[(64 - h) * 64] = Pv + Qv;
    }
  }
}

extern "C" void kernel_launch(void* const* d_in, const int* in_sizes, int n_in,
                              void* d_out, int out_size, void* d_ws,
                              size_t ws_size, hipStream_t stream) {
  const float* x    = (const float*)d_in[0];
  const float* Uin  = (const float*)d_in[1];
  const float* Uout = (const float*)d_in[2];
  const float* Uz   = (const float*)d_in[3];
  const float* Uh   = (const float*)d_in[4];
  const float* Uw   = (const float*)d_in[5];
  const float* Uz2  = (const float*)d_in[6];
  const float* Uh2  = (const float*)d_in[7];
  const float* cr   = (const float*)d_in[8];
  const float* ci   = (const float*)d_in[9];
  const float* c2r  = (const float*)d_in[10];
  const float* c2i  = (const float*)d_in[11];
  float* outp = (float*)d_out;

  char* ws = (char*)d_ws;
  float* S       = (float*)ws;            // 4 floats
  float* partial = (float*)(ws + 256);    // 256 floats
  float2* A2 = (float2*)(ws + 4096);                 // 33,554,432 B
  float2* P  = (float2*)(ws + 33558528);             //  8,388,608 B
  float2* Q  = (float2*)(ws + 41947136);             // 16,777,216 B

  k_fwd_wh_core<<<4352, 256, 0, stream>>>(x, A2, cr, ci, c2r, c2i, partial);
  k_proj<<<dim3(256, 2), 256, 0, stream>>>(A2, P, Uin, partial, S);
  k_zmix<<<dim3(64, 4), 256, 0, stream>>>(P, Q, Uz, Uh, Uw, Uz2, Uh2, S);
  k_inv_hw_ex<<<dim3(256, 4), 256, 0, stream>>>(Q, outp, Uout);
}